// Round 1
// baseline (3060.484 us; speedup 1.0000x reference)
//
#include <hip/hip_runtime.h>

#define BATCH 65536
#define SEQ 14
#define IN 24
#define H 64
#define LAYERS 3
#define CLS 10

__device__ __forceinline__ float fast_tanh(float v) {
    // tanh(v) = 1 - 2/(exp(2v)+1); saturates correctly for |v| large.
    float e = __expf(2.0f * v);
    return 1.0f - 2.0f * __builtin_amdgcn_rcpf(e + 1.0f);
}

// One recurrent layer step: h = tanh(in @ Wi^T + b_i + h @ Wh^T + b_h)
// K = input width. `in` and `h` are register arrays (statically indexed).
// hrow = this thread's private padded LDS row (runtime-indexed store).
template<int K>
__device__ __forceinline__ void rnn_step(const float* __restrict__ Wi,
                                         const float* __restrict__ Wh,
                                         const float* __restrict__ bi,
                                         const float* __restrict__ bh,
                                         const float (&in)[K],
                                         float (&h)[H],
                                         float* __restrict__ hrow) {
#pragma unroll 2
    for (int i = 0; i < H; ++i) {
        const float* wi = Wi + i * K;   // wave-uniform -> s_load
        const float* wh = Wh + i * H;   // wave-uniform -> s_load
        float a0 = bi[i], a1 = bh[i], a2 = 0.f, a3 = 0.f;
#pragma unroll
        for (int k = 0; k < K; k += 4) {
            a0 += wi[k + 0] * in[k + 0];
            a1 += wi[k + 1] * in[k + 1];
            a2 += wi[k + 2] * in[k + 2];
            a3 += wi[k + 3] * in[k + 3];
        }
#pragma unroll
        for (int j = 0; j < H; j += 4) {
            a0 += wh[j + 0] * h[j + 0];
            a1 += wh[j + 1] * h[j + 1];
            a2 += wh[j + 2] * h[j + 2];
            a3 += wh[j + 3] * h[j + 3];
        }
        hrow[i] = fast_tanh((a0 + a1) + (a2 + a3));
    }
    // Copy back to registers with static indexing (LDS row is thread-private,
    // no barrier needed; compiler inserts lgkmcnt waits).
#pragma unroll
    for (int j = 0; j < H; ++j) h[j] = hrow[j];
}

__global__ __launch_bounds__(128, 2) void rnn_fused(
    const float* __restrict__ x,     // [B, T, 24]
    const float* __restrict__ h0in,  // [3, B, 64]
    const float* __restrict__ Wi0, const float* __restrict__ Wh0,
    const float* __restrict__ bi0, const float* __restrict__ bh0,
    const float* __restrict__ Wi1, const float* __restrict__ Wh1,
    const float* __restrict__ bi1, const float* __restrict__ bh1,
    const float* __restrict__ Wi2, const float* __restrict__ Wh2,
    const float* __restrict__ bi2, const float* __restrict__ bh2,
    const float* __restrict__ Wout, const float* __restrict__ bout,
    float* __restrict__ out)         // [B*10] ++ [3*B*64]
{
    __shared__ float hnew[128][H + 1];  // stride 65 floats: conflict-free
    const int tid = threadIdx.x;
    const int b = blockIdx.x * blockDim.x + tid;
    float* hrow = &hnew[tid][0];

    float h0[H], h1[H], h2[H];
    {
        const float4* p0 = (const float4*)(h0in + (size_t)0 * BATCH * H + (size_t)b * H);
        const float4* p1 = (const float4*)(h0in + (size_t)1 * BATCH * H + (size_t)b * H);
        const float4* p2 = (const float4*)(h0in + (size_t)2 * BATCH * H + (size_t)b * H);
#pragma unroll
        for (int j = 0; j < H / 4; ++j) {
            float4 v0 = p0[j], v1 = p1[j], v2 = p2[j];
            h0[4 * j + 0] = v0.x; h0[4 * j + 1] = v0.y; h0[4 * j + 2] = v0.z; h0[4 * j + 3] = v0.w;
            h1[4 * j + 0] = v1.x; h1[4 * j + 1] = v1.y; h1[4 * j + 2] = v1.z; h1[4 * j + 3] = v1.w;
            h2[4 * j + 0] = v2.x; h2[4 * j + 1] = v2.y; h2[4 * j + 2] = v2.z; h2[4 * j + 3] = v2.w;
        }
    }

#pragma unroll 1
    for (int t = 0; t < SEQ; ++t) {
        float xv[IN];
        const float* xp = x + ((size_t)b * SEQ + t) * IN;
#pragma unroll
        for (int k = 0; k < IN; k += 4) {
            float4 v = *(const float4*)(xp + k);
            xv[k + 0] = v.x; xv[k + 1] = v.y; xv[k + 2] = v.z; xv[k + 3] = v.w;
        }
        rnn_step<IN>(Wi0, Wh0, bi0, bh0, xv, h0, hrow);
        rnn_step<H>(Wi1, Wh1, bi1, bh1, h0, h1, hrow);
        rnn_step<H>(Wi2, Wh2, bi2, bh2, h1, h2, hrow);
    }

    // Output head: logits = h2 @ Wout^T + bout
#pragma unroll
    for (int c = 0; c < CLS; ++c) {
        const float* wo = Wout + c * H;  // uniform
        float a0 = bout[c], a1 = 0.f, a2 = 0.f, a3 = 0.f;
#pragma unroll
        for (int j = 0; j < H; j += 4) {
            a0 += wo[j + 0] * h2[j + 0];
            a1 += wo[j + 1] * h2[j + 1];
            a2 += wo[j + 2] * h2[j + 2];
            a3 += wo[j + 3] * h2[j + 3];
        }
        out[(size_t)b * CLS + c] = (a0 + a1) + (a2 + a3);
    }

    // Final hidden states: out[B*CLS + l*B*H + b*H + j]
    float* hs = out + (size_t)BATCH * CLS;
#pragma unroll
    for (int j = 0; j < H; j += 4) {
        *(float4*)(hs + (size_t)0 * BATCH * H + (size_t)b * H + j) =
            make_float4(h0[j], h0[j + 1], h0[j + 2], h0[j + 3]);
        *(float4*)(hs + (size_t)1 * BATCH * H + (size_t)b * H + j) =
            make_float4(h1[j], h1[j + 1], h1[j + 2], h1[j + 3]);
        *(float4*)(hs + (size_t)2 * BATCH * H + (size_t)b * H + j) =
            make_float4(h2[j], h2[j + 1], h2[j + 2], h2[j + 3]);
    }
}

extern "C" void kernel_launch(void* const* d_in, const int* in_sizes, int n_in,
                              void* d_out, int out_size, void* d_ws, size_t ws_size,
                              hipStream_t stream) {
    const float* x    = (const float*)d_in[0];
    const float* h0in = (const float*)d_in[1];
    const float* Wi0  = (const float*)d_in[2];
    const float* Wh0  = (const float*)d_in[3];
    const float* bi0  = (const float*)d_in[4];
    const float* bh0  = (const float*)d_in[5];
    const float* Wi1  = (const float*)d_in[6];
    const float* Wh1  = (const float*)d_in[7];
    const float* bi1  = (const float*)d_in[8];
    const float* bh1  = (const float*)d_in[9];
    const float* Wi2  = (const float*)d_in[10];
    const float* Wh2  = (const float*)d_in[11];
    const float* bi2  = (const float*)d_in[12];
    const float* bh2  = (const float*)d_in[13];
    const float* Wout = (const float*)d_in[14];
    const float* bout = (const float*)d_in[15];
    float* out = (float*)d_out;

    dim3 grid(BATCH / 128), block(128);
    rnn_fused<<<grid, block, 0, stream>>>(x, h0in, Wi0, Wh0, bi0, bh0,
                                          Wi1, Wh1, bi1, bh1,
                                          Wi2, Wh2, bi2, bh2,
                                          Wout, bout, out);
}

// Round 2
// 1802.426 us; speedup vs baseline: 1.6980x; 1.6980x over previous
//
#include <hip/hip_runtime.h>

#define BATCH 65536
#define SEQ 14
#define IN 24
#define H 64
#define LAYERS 3
#define CLS 10

__device__ __forceinline__ float fast_tanh(float v) {
    // tanh(v) = 1 - 2/(exp(2v)+1); saturates correctly for |v| large.
    float e = __expf(2.0f * v);
    return 1.0f - 2.0f * __builtin_amdgcn_rcpf(e + 1.0f);
}

// One recurrent layer step: h = tanh(in @ Wi^T + b_i + h @ Wh^T + b_h)
// K = input width. `in` and `h` are register arrays (statically indexed).
// hrow = this thread's private padded LDS row (runtime-indexed store only).
template<int K>
__device__ __forceinline__ void rnn_step(const float* __restrict__ Wi,
                                         const float* __restrict__ Wh,
                                         const float* __restrict__ bi,
                                         const float* __restrict__ bh,
                                         const float (&in)[K],
                                         float (&h)[H],
                                         float* __restrict__ hrow) {
#pragma unroll 2
    for (int i = 0; i < H; ++i) {
        const float* wi = Wi + i * K;   // wave-uniform -> s_load
        const float* wh = Wh + i * H;   // wave-uniform -> s_load
        float a0 = bi[i], a1 = bh[i], a2 = 0.f, a3 = 0.f;
#pragma unroll
        for (int k = 0; k < K; k += 4) {
            a0 += wi[k + 0] * in[k + 0];
            a1 += wi[k + 1] * in[k + 1];
            a2 += wi[k + 2] * in[k + 2];
            a3 += wi[k + 3] * in[k + 3];
        }
#pragma unroll
        for (int j = 0; j < H; j += 4) {
            a0 += wh[j + 0] * h[j + 0];
            a1 += wh[j + 1] * h[j + 1];
            a2 += wh[j + 2] * h[j + 2];
            a3 += wh[j + 3] * h[j + 3];
        }
        hrow[i] = fast_tanh((a0 + a1) + (a2 + a3));
    }
    // Copy back to registers with static indexing (LDS row is thread-private,
    // no barrier needed; compiler inserts lgkmcnt waits).
#pragma unroll
    for (int j = 0; j < H; ++j) h[j] = hrow[j];
}

__global__ __launch_bounds__(64, 1) void rnn_fused(
    const float* __restrict__ x,     // [B, T, 24]
    const float* __restrict__ h0in,  // [3, B, 64]
    const float* __restrict__ Wi0, const float* __restrict__ Wh0,
    const float* __restrict__ bi0, const float* __restrict__ bh0,
    const float* __restrict__ Wi1, const float* __restrict__ Wh1,
    const float* __restrict__ bi1, const float* __restrict__ bh1,
    const float* __restrict__ Wi2, const float* __restrict__ Wh2,
    const float* __restrict__ bi2, const float* __restrict__ bh2,
    const float* __restrict__ Wout, const float* __restrict__ bout,
    float* __restrict__ out)         // [B*10] ++ [3*B*64]
{
    __shared__ float hnew[64][H + 1];  // stride 65 floats: conflict-free
    const int tid = threadIdx.x;
    const int b = blockIdx.x * blockDim.x + tid;
    float* hrow = &hnew[tid][0];

    float h0[H], h1[H], h2[H];
    {
        const float4* p0 = (const float4*)(h0in + (size_t)0 * BATCH * H + (size_t)b * H);
        const float4* p1 = (const float4*)(h0in + (size_t)1 * BATCH * H + (size_t)b * H);
        const float4* p2 = (const float4*)(h0in + (size_t)2 * BATCH * H + (size_t)b * H);
#pragma unroll
        for (int j = 0; j < H / 4; ++j) {
            float4 v0 = p0[j], v1 = p1[j], v2 = p2[j];
            h0[4 * j + 0] = v0.x; h0[4 * j + 1] = v0.y; h0[4 * j + 2] = v0.z; h0[4 * j + 3] = v0.w;
            h1[4 * j + 0] = v1.x; h1[4 * j + 1] = v1.y; h1[4 * j + 2] = v1.z; h1[4 * j + 3] = v1.w;
            h2[4 * j + 0] = v2.x; h2[4 * j + 1] = v2.y; h2[4 * j + 2] = v2.z; h2[4 * j + 3] = v2.w;
        }
    }

#pragma unroll 1
    for (int t = 0; t < SEQ; ++t) {
        float xv[IN];
        const float* xp = x + ((size_t)b * SEQ + t) * IN;
#pragma unroll
        for (int k = 0; k < IN; k += 4) {
            float4 v = *(const float4*)(xp + k);
            xv[k + 0] = v.x; xv[k + 1] = v.y; xv[k + 2] = v.z; xv[k + 3] = v.w;
        }
        rnn_step<IN>(Wi0, Wh0, bi0, bh0, xv, h0, hrow);
        rnn_step<H>(Wi1, Wh1, bi1, bh1, h0, h1, hrow);
        rnn_step<H>(Wi2, Wh2, bi2, bh2, h1, h2, hrow);
    }

    // Output head: logits = h2 @ Wout^T + bout
#pragma unroll
    for (int c = 0; c < CLS; ++c) {
        const float* wo = Wout + c * H;  // uniform
        float a0 = bout[c], a1 = 0.f, a2 = 0.f, a3 = 0.f;
#pragma unroll
        for (int j = 0; j < H; j += 4) {
            a0 += wo[j + 0] * h2[j + 0];
            a1 += wo[j + 1] * h2[j + 1];
            a2 += wo[j + 2] * h2[j + 2];
            a3 += wo[j + 3] * h2[j + 3];
        }
        out[(size_t)b * CLS + c] = (a0 + a1) + (a2 + a3);
    }

    // Final hidden states: out[B*CLS + l*B*H + b*H + j]
    float* hs = out + (size_t)BATCH * CLS;
#pragma unroll
    for (int j = 0; j < H; j += 4) {
        *(float4*)(hs + (size_t)0 * BATCH * H + (size_t)b * H + j) =
            make_float4(h0[j], h0[j + 1], h0[j + 2], h0[j + 3]);
        *(float4*)(hs + (size_t)1 * BATCH * H + (size_t)b * H + j) =
            make_float4(h1[j], h1[j + 1], h1[j + 2], h1[j + 3]);
        *(float4*)(hs + (size_t)2 * BATCH * H + (size_t)b * H + j) =
            make_float4(h2[j], h2[j + 1], h2[j + 2], h2[j + 3]);
    }
}

extern "C" void kernel_launch(void* const* d_in, const int* in_sizes, int n_in,
                              void* d_out, int out_size, void* d_ws, size_t ws_size,
                              hipStream_t stream) {
    const float* x    = (const float*)d_in[0];
    const float* h0in = (const float*)d_in[1];
    const float* Wi0  = (const float*)d_in[2];
    const float* Wh0  = (const float*)d_in[3];
    const float* bi0  = (const float*)d_in[4];
    const float* bh0  = (const float*)d_in[5];
    const float* Wi1  = (const float*)d_in[6];
    const float* Wh1  = (const float*)d_in[7];
    const float* bi1  = (const float*)d_in[8];
    const float* bh1  = (const float*)d_in[9];
    const float* Wi2  = (const float*)d_in[10];
    const float* Wh2  = (const float*)d_in[11];
    const float* bi2  = (const float*)d_in[12];
    const float* bh2  = (const float*)d_in[13];
    const float* Wout = (const float*)d_in[14];
    const float* bout = (const float*)d_in[15];
    float* out = (float*)d_out;

    dim3 grid(BATCH / 64), block(64);
    rnn_fused<<<grid, block, 0, stream>>>(x, h0in, Wi0, Wh0, bi0, bh0,
                                          Wi1, Wh1, bi1, bh1,
                                          Wi2, Wh2, bi2, bh2,
                                          Wout, bout, out);
}

// Round 3
// 151.219 us; speedup vs baseline: 20.2387x; 11.9193x over previous
//
#include <hip/hip_runtime.h>

#define SEQ 14
#define IN 24
#define H 64
#define CLS 10
#define NBATCH 65536

typedef __attribute__((ext_vector_type(4))) float f32x4;
typedef __attribute__((ext_vector_type(8))) short bf16x8;
typedef __attribute__((ext_vector_type(4))) short bf16x4;

#define MFMA(A, B, C) __builtin_amdgcn_mfma_f32_16x16x32_bf16(A, B, C, 0, 0, 0)

static __device__ __forceinline__ short f2bf(float f) {
    union { float f; unsigned u; } a; a.f = f;
    unsigned r = (a.u + 0x7FFFu + ((a.u >> 16) & 1u)) >> 16;  // RNE
    return (short)r;
}
static __device__ __forceinline__ float bf2f(short s) {
    union { unsigned u; float f; } a;
    a.u = ((unsigned)(unsigned short)s) << 16;
    return a.f;
}
static __device__ __forceinline__ float fast_tanh(float v) {
    float e = __expf(2.0f * v);
    return 1.0f - 2.0f / (e + 1.0f);
}
static __device__ __forceinline__ bf16x8 pack8(f32x4 a, f32x4 b) {
    bf16x8 r;
    r[0] = f2bf(a[0]); r[1] = f2bf(a[1]); r[2] = f2bf(a[2]); r[3] = f2bf(a[3]);
    r[4] = f2bf(b[0]); r[5] = f2bf(b[1]); r[6] = f2bf(b[2]); r[7] = f2bf(b[3]);
    return r;
}
static __device__ __forceinline__ bf16x8 loadw8(const float* p) {
    f32x4 v0 = *(const f32x4*)p;
    f32x4 v1 = *(const f32x4*)(p + 4);
    return pack8(v0, v1);
}

// WG = 256 threads = 4 waves, 32 batch elems. wave = m-tile (16 i-rows).
// A = weights (VGPR, bf16), B = activations (LDS, bf16), D = preact (f32).
// D layout (HW-verified): col(batch)=lane&15, row(i)=(lane>>4)*4+reg.
__global__ __launch_bounds__(256, 4) void rnn_mfma(
    const float* __restrict__ x,     // [B, T, 24]
    const float* __restrict__ h0in,  // [3, B, 64]
    const float* __restrict__ pWi0, const float* __restrict__ pWh0,
    const float* __restrict__ pbi0, const float* __restrict__ pbh0,
    const float* __restrict__ pWi1, const float* __restrict__ pWh1,
    const float* __restrict__ pbi1, const float* __restrict__ pbh1,
    const float* __restrict__ pWi2, const float* __restrict__ pWh2,
    const float* __restrict__ pbi2, const float* __restrict__ pbh2,
    const float* __restrict__ pWout, const float* __restrict__ pbout,
    float* __restrict__ out)         // [B*10] ++ [3*B*64]
{
    __shared__ __align__(16) short hbuf[3][8][32][8];  // [layer][kg][b][elem] bf16

    const int tid  = threadIdx.x;
    const int lane = tid & 63;
    const int g    = lane >> 4;      // k-group 0..3
    const int ln   = lane & 15;      // A-row-within-tile / B-col-within-tile
    const int mt   = tid >> 6;       // wave id = m-tile 0..3
    const int Bb   = blockIdx.x * 32;

    // ---- init hbuf from h0 (bf16) ----
    {
        const int b = tid & 31, k8 = (tid >> 5) & 7;
#pragma unroll
        for (int l = 0; l < 3; ++l) {
            const float* p = h0in + ((size_t)l * NBATCH + (Bb + b)) * H + k8 * 8;
            f32x4 v0 = *(const f32x4*)p, v1 = *(const f32x4*)(p + 4);
            *(bf16x8*)&hbuf[l][k8][b][0] = pack8(v0, v1);
        }
    }

    // ---- weight A-fragments (bf16, VGPR-resident) ----
    const int ia = mt * 16 + ln;     // global i-row this lane supplies for A
    bf16x8 aWi0;
    if (g < 3) aWi0 = loadw8(pWi0 + ia * IN + g * 8);
    else {
#pragma unroll
        for (int j = 0; j < 8; ++j) aWi0[j] = 0;   // k = 24..31 zero pad
    }
    bf16x8 aWh0[2], aWi1[2], aWh1[2], aWi2[2], aWh2[2];
#pragma unroll
    for (int kt = 0; kt < 2; ++kt) {
        aWh0[kt] = loadw8(pWh0 + ia * H + kt * 32 + g * 8);
        aWi1[kt] = loadw8(pWi1 + ia * H + kt * 32 + g * 8);
        aWh1[kt] = loadw8(pWh1 + ia * H + kt * 32 + g * 8);
        aWi2[kt] = loadw8(pWi2 + ia * H + kt * 32 + g * 8);
        aWh2[kt] = loadw8(pWh2 + ia * H + kt * 32 + g * 8);
    }

    // ---- bias sums per D-row: i0 = mt*16 + g*4 + r ----
    const int i0 = mt * 16 + g * 4;
    f32x4 bs0 = *(const f32x4*)(pbi0 + i0);
    f32x4 bs1 = *(const f32x4*)(pbi1 + i0);
    f32x4 bs2 = *(const f32x4*)(pbi2 + i0);
    bs0 += *(const f32x4*)(pbh0 + i0);
    bs1 += *(const f32x4*)(pbh1 + i0);
    bs2 += *(const f32x4*)(pbh2 + i0);

    const int kgw = mt * 2 + (g >> 1);   // epilogue write kg
    const int eb  = (g & 1) * 4;         // epilogue write elem base

    const float* xb0 = x + (size_t)(Bb + ln) * (SEQ * IN) + g * 8;        // nt0
    const float* xb1 = x + (size_t)(Bb + ln + 16) * (SEQ * IN) + g * 8;   // nt1
    float* hsout = out + (size_t)NBATCH * CLS;

    __syncthreads();

#pragma unroll 1
    for (int t = 0; t < SEQ; ++t) {
        // ================= L0: below = x (global), self = hbuf[0] =================
        {
            bf16x8 bx0, bx1;
#pragma unroll
            for (int j = 0; j < 8; ++j) { bx0[j] = 0; bx1[j] = 0; }
            if (g < 3) {
                const float* p0 = xb0 + t * IN;
                const float* p1 = xb1 + t * IN;
                bx0 = pack8(*(const f32x4*)p0, *(const f32x4*)(p0 + 4));
                bx1 = pack8(*(const f32x4*)p1, *(const f32x4*)(p1 + 4));
            }
            bf16x8 s0a = *(const bf16x8*)&hbuf[0][g][ln][0];
            bf16x8 s0b = *(const bf16x8*)&hbuf[0][g][ln + 16][0];
            bf16x8 s1a = *(const bf16x8*)&hbuf[0][4 + g][ln][0];
            bf16x8 s1b = *(const bf16x8*)&hbuf[0][4 + g][ln + 16][0];
            f32x4 a0 = {0.f, 0.f, 0.f, 0.f}, a1 = {0.f, 0.f, 0.f, 0.f};
            a0 = MFMA(aWh0[0], s0a, a0);  a1 = MFMA(aWh0[0], s0b, a1);
            a0 = MFMA(aWh0[1], s1a, a0);  a1 = MFMA(aWh0[1], s1b, a1);
            a0 = MFMA(aWi0,    bx0, a0);  a1 = MFMA(aWi0,    bx1, a1);
            f32x4 t0, t1;
#pragma unroll
            for (int r = 0; r < 4; ++r) {
                t0[r] = fast_tanh(a0[r] + bs0[r]);
                t1[r] = fast_tanh(a1[r] + bs0[r]);
            }
            if (t == SEQ - 1) {
                float* hp = hsout;  // layer 0
                *(f32x4*)(hp + (size_t)(Bb + ln) * H + i0) = t0;
                *(f32x4*)(hp + (size_t)(Bb + ln + 16) * H + i0) = t1;
            }
            bf16x4 p0, p1;
#pragma unroll
            for (int r = 0; r < 4; ++r) { p0[r] = f2bf(t0[r]); p1[r] = f2bf(t1[r]); }
            __syncthreads();   // all reads of hbuf[0] done
            *(bf16x4*)&hbuf[0][kgw][ln][eb] = p0;
            *(bf16x4*)&hbuf[0][kgw][ln + 16][eb] = p1;
            __syncthreads();   // writes visible
        }
        // ================= L1: below = hbuf[0], self = hbuf[1] =================
        {
            bf16x8 s0a = *(const bf16x8*)&hbuf[1][g][ln][0];
            bf16x8 s0b = *(const bf16x8*)&hbuf[1][g][ln + 16][0];
            bf16x8 s1a = *(const bf16x8*)&hbuf[1][4 + g][ln][0];
            bf16x8 s1b = *(const bf16x8*)&hbuf[1][4 + g][ln + 16][0];
            bf16x8 b0a = *(const bf16x8*)&hbuf[0][g][ln][0];
            bf16x8 b0b = *(const bf16x8*)&hbuf[0][g][ln + 16][0];
            bf16x8 b1a = *(const bf16x8*)&hbuf[0][4 + g][ln][0];
            bf16x8 b1b = *(const bf16x8*)&hbuf[0][4 + g][ln + 16][0];
            f32x4 a0 = {0.f, 0.f, 0.f, 0.f}, a1 = {0.f, 0.f, 0.f, 0.f};
            a0 = MFMA(aWh1[0], s0a, a0);  a1 = MFMA(aWh1[0], s0b, a1);
            a0 = MFMA(aWh1[1], s1a, a0);  a1 = MFMA(aWh1[1], s1b, a1);
            a0 = MFMA(aWi1[0], b0a, a0);  a1 = MFMA(aWi1[0], b0b, a1);
            a0 = MFMA(aWi1[1], b1a, a0);  a1 = MFMA(aWi1[1], b1b, a1);
            f32x4 t0, t1;
#pragma unroll
            for (int r = 0; r < 4; ++r) {
                t0[r] = fast_tanh(a0[r] + bs1[r]);
                t1[r] = fast_tanh(a1[r] + bs1[r]);
            }
            if (t == SEQ - 1) {
                float* hp = hsout + (size_t)NBATCH * H;  // layer 1
                *(f32x4*)(hp + (size_t)(Bb + ln) * H + i0) = t0;
                *(f32x4*)(hp + (size_t)(Bb + ln + 16) * H + i0) = t1;
            }
            bf16x4 p0, p1;
#pragma unroll
            for (int r = 0; r < 4; ++r) { p0[r] = f2bf(t0[r]); p1[r] = f2bf(t1[r]); }
            __syncthreads();
            *(bf16x4*)&hbuf[1][kgw][ln][eb] = p0;
            *(bf16x4*)&hbuf[1][kgw][ln + 16][eb] = p1;
            __syncthreads();
        }
        // ================= L2: below = hbuf[1], self = hbuf[2] =================
        {
            bf16x8 s0a = *(const bf16x8*)&hbuf[2][g][ln][0];
            bf16x8 s0b = *(const bf16x8*)&hbuf[2][g][ln + 16][0];
            bf16x8 s1a = *(const bf16x8*)&hbuf[2][4 + g][ln][0];
            bf16x8 s1b = *(const bf16x8*)&hbuf[2][4 + g][ln + 16][0];
            bf16x8 b0a = *(const bf16x8*)&hbuf[1][g][ln][0];
            bf16x8 b0b = *(const bf16x8*)&hbuf[1][g][ln + 16][0];
            bf16x8 b1a = *(const bf16x8*)&hbuf[1][4 + g][ln][0];
            bf16x8 b1b = *(const bf16x8*)&hbuf[1][4 + g][ln + 16][0];
            f32x4 a0 = {0.f, 0.f, 0.f, 0.f}, a1 = {0.f, 0.f, 0.f, 0.f};
            a0 = MFMA(aWh2[0], s0a, a0);  a1 = MFMA(aWh2[0], s0b, a1);
            a0 = MFMA(aWh2[1], s1a, a0);  a1 = MFMA(aWh2[1], s1b, a1);
            a0 = MFMA(aWi2[0], b0a, a0);  a1 = MFMA(aWi2[0], b0b, a1);
            a0 = MFMA(aWi2[1], b1a, a0);  a1 = MFMA(aWi2[1], b1b, a1);
            f32x4 t0, t1;
#pragma unroll
            for (int r = 0; r < 4; ++r) {
                t0[r] = fast_tanh(a0[r] + bs2[r]);
                t1[r] = fast_tanh(a1[r] + bs2[r]);
            }
            if (t == SEQ - 1) {
                float* hp = hsout + (size_t)2 * NBATCH * H;  // layer 2
                *(f32x4*)(hp + (size_t)(Bb + ln) * H + i0) = t0;
                *(f32x4*)(hp + (size_t)(Bb + ln + 16) * H + i0) = t1;
            }
            bf16x4 p0, p1;
#pragma unroll
            for (int r = 0; r < 4; ++r) { p0[r] = f2bf(t0[r]); p1[r] = f2bf(t1[r]); }
            __syncthreads();
            *(bf16x4*)&hbuf[2][kgw][ln][eb] = p0;
            *(bf16x4*)&hbuf[2][kgw][ln + 16][eb] = p1;
            __syncthreads();
        }
    }

    // ================= logits head (f32 weights, bf16 h2) =================
    {
        const int b  = tid & 31;
        const int c0 = tid >> 5;   // 0..7
        float hv[H];
#pragma unroll
        for (int kg = 0; kg < 8; ++kg) {
            bf16x8 v = *(const bf16x8*)&hbuf[2][kg][b][0];
#pragma unroll
            for (int j = 0; j < 8; ++j) hv[kg * 8 + j] = bf2f(v[j]);
        }
#pragma unroll 1
        for (int c = c0; c < CLS; c += 8) {
            const float* w = pWout + c * H;
            float a = pbout[c];
#pragma unroll
            for (int j = 0; j < H; ++j) a += w[j] * hv[j];
            out[(size_t)(Bb + b) * CLS + c] = a;
        }
    }
}

extern "C" void kernel_launch(void* const* d_in, const int* in_sizes, int n_in,
                              void* d_out, int out_size, void* d_ws, size_t ws_size,
                              hipStream_t stream) {
    const float* x    = (const float*)d_in[0];
    const float* h0in = (const float*)d_in[1];
    const float* Wi0  = (const float*)d_in[2];
    const float* Wh0  = (const float*)d_in[3];
    const float* bi0  = (const float*)d_in[4];
    const float* bh0  = (const float*)d_in[5];
    const float* Wi1  = (const float*)d_in[6];
    const float* Wh1  = (const float*)d_in[7];
    const float* bi1  = (const float*)d_in[8];
    const float* bh1  = (const float*)d_in[9];
    const float* Wi2  = (const float*)d_in[10];
    const float* Wh2  = (const float*)d_in[11];
    const float* bi2  = (const float*)d_in[12];
    const float* bh2  = (const float*)d_in[13];
    const float* Wout = (const float*)d_in[14];
    const float* bout = (const float*)d_in[15];
    float* out = (float*)d_out;

    dim3 grid(NBATCH / 32), block(256);
    rnn_mfma<<<grid, block, 0, stream>>>(x, h0in, Wi0, Wh0, bi0, bh0,
                                         Wi1, Wh1, bi1, bh1,
                                         Wi2, Wh2, bi2, bh2,
                                         Wout, bout, out);
}

// Round 4
// 129.772 us; speedup vs baseline: 23.5835x; 1.1653x over previous
//
#include <hip/hip_runtime.h>
#include <hip/hip_bf16.h>

#define SEQ 14
#define IN 24
#define H 64
#define CLS 10
#define NBATCH 65536

typedef __attribute__((ext_vector_type(4))) float f32x4;
typedef __attribute__((ext_vector_type(8))) short bf16x8;
typedef __attribute__((ext_vector_type(4))) short bf16x4;

#define MFMA(A, B, C) __builtin_amdgcn_mfma_f32_16x16x32_bf16(A, B, C, 0, 0, 0)

static __device__ __forceinline__ short f2bf(float f) {
    // Native cast -> compiler emits v_cvt_pk_bf16_f32 for pairs (m240).
    __hip_bfloat16 h = __float2bfloat16(f);
    union { __hip_bfloat16 h; short s; } u; u.h = h;
    return u.s;
}
static __device__ __forceinline__ float bf2f(short s) {
    union { unsigned u; float f; } a;
    a.u = ((unsigned)(unsigned short)s) << 16;
    return a.f;
}
static __device__ __forceinline__ float fast_tanh(float v) {
    // tanh(v) = 1 - 2/(exp(2v)+1); v_rcp (22-bit) not full-precision divide.
    float e = __expf(2.0f * v);
    return 1.0f - 2.0f * __builtin_amdgcn_rcpf(e + 1.0f);
}
static __device__ __forceinline__ bf16x8 pack8(f32x4 a, f32x4 b) {
    bf16x8 r;
    r[0] = f2bf(a[0]); r[1] = f2bf(a[1]); r[2] = f2bf(a[2]); r[3] = f2bf(a[3]);
    r[4] = f2bf(b[0]); r[5] = f2bf(b[1]); r[6] = f2bf(b[2]); r[7] = f2bf(b[3]);
    return r;
}
static __device__ __forceinline__ bf16x8 loadw8(const float* p) {
    f32x4 v0 = *(const f32x4*)p;
    f32x4 v1 = *(const f32x4*)(p + 4);
    return pack8(v0, v1);
}

// WG = 256 threads = 4 waves, 32 batch elems. wave = m-tile (16 i-rows).
// A = weights (VGPR, bf16), B = activations (LDS, bf16), D = preact (f32).
// D layout (HW-verified): col(batch)=lane&15, row(i)=(lane>>4)*4+reg.
// hbuf double-buffered on t-parity: one barrier per layer-step (RAW only;
// WAR is safe because step-t readers of buf[p] all precede the first barrier
// after which buf[p] is rewritten at t+1).
__global__ __launch_bounds__(256, 6) void rnn_mfma(
    const float* __restrict__ x,     // [B, T, 24]
    const float* __restrict__ h0in,  // [3, B, 64]
    const float* __restrict__ pWi0, const float* __restrict__ pWh0,
    const float* __restrict__ pbi0, const float* __restrict__ pbh0,
    const float* __restrict__ pWi1, const float* __restrict__ pWh1,
    const float* __restrict__ pbi1, const float* __restrict__ pbh1,
    const float* __restrict__ pWi2, const float* __restrict__ pWh2,
    const float* __restrict__ pbi2, const float* __restrict__ pbh2,
    const float* __restrict__ pWout, const float* __restrict__ pbout,
    float* __restrict__ out)         // [B*10] ++ [3*B*64]
{
    __shared__ __align__(16) short hbuf[2][3][8][32][8];  // [par][layer][kg][b][e]

    const int tid  = threadIdx.x;
    const int lane = tid & 63;
    const int g    = lane >> 4;      // k-group 0..3
    const int ln   = lane & 15;      // A-row-within-tile / B-col-within-tile
    const int mt   = tid >> 6;       // wave id = m-tile 0..3
    const int Bb   = blockIdx.x * 32;

    // ---- init hbuf parity 0 from h0 (bf16) ----
    {
        const int b = tid & 31, k8 = (tid >> 5) & 7;
#pragma unroll
        for (int l = 0; l < 3; ++l) {
            const float* p = h0in + ((size_t)l * NBATCH + (Bb + b)) * H + k8 * 8;
            f32x4 v0 = *(const f32x4*)p, v1 = *(const f32x4*)(p + 4);
            *(bf16x8*)&hbuf[0][l][k8][b][0] = pack8(v0, v1);
        }
    }

    // ---- weight A-fragments (bf16, VGPR-resident) ----
    const int ia = mt * 16 + ln;     // global i-row this lane supplies for A
    bf16x8 aWi0;
    if (g < 3) aWi0 = loadw8(pWi0 + ia * IN + g * 8);
    else {
#pragma unroll
        for (int j = 0; j < 8; ++j) aWi0[j] = 0;   // k = 24..31 zero pad
    }
    bf16x8 aWh0[2], aWi1[2], aWh1[2], aWi2[2], aWh2[2];
#pragma unroll
    for (int kt = 0; kt < 2; ++kt) {
        aWh0[kt] = loadw8(pWh0 + ia * H + kt * 32 + g * 8);
        aWi1[kt] = loadw8(pWi1 + ia * H + kt * 32 + g * 8);
        aWh1[kt] = loadw8(pWh1 + ia * H + kt * 32 + g * 8);
        aWi2[kt] = loadw8(pWi2 + ia * H + kt * 32 + g * 8);
        aWh2[kt] = loadw8(pWh2 + ia * H + kt * 32 + g * 8);
    }

    // ---- bias sums per D-row: i0 = mt*16 + g*4 + r ----
    const int i0 = mt * 16 + g * 4;
    f32x4 bs0 = *(const f32x4*)(pbi0 + i0);
    f32x4 bs1 = *(const f32x4*)(pbi1 + i0);
    f32x4 bs2 = *(const f32x4*)(pbi2 + i0);
    bs0 += *(const f32x4*)(pbh0 + i0);
    bs1 += *(const f32x4*)(pbh1 + i0);
    bs2 += *(const f32x4*)(pbh2 + i0);

    const int kgw = mt * 2 + (g >> 1);   // epilogue write kg
    const int eb  = (g & 1) * 4;         // epilogue write elem base

    const float* xb0 = x + (size_t)(Bb + ln) * (SEQ * IN) + g * 8;        // nt0
    const float* xb1 = x + (size_t)(Bb + ln + 16) * (SEQ * IN) + g * 8;   // nt1
    float* hsout = out + (size_t)NBATCH * CLS;

    __syncthreads();

#pragma unroll 1
    for (int t = 0; t < SEQ; ++t) {
        const int p = t & 1, q = p ^ 1;
        // ============ L0: below = x (global), self = hbuf[p][0] -> hbuf[q][0]
        {
            bf16x8 bx0, bx1;
#pragma unroll
            for (int j = 0; j < 8; ++j) { bx0[j] = 0; bx1[j] = 0; }
            if (g < 3) {
                const float* p0 = xb0 + t * IN;
                const float* p1 = xb1 + t * IN;
                bx0 = pack8(*(const f32x4*)p0, *(const f32x4*)(p0 + 4));
                bx1 = pack8(*(const f32x4*)p1, *(const f32x4*)(p1 + 4));
            }
            bf16x8 s0a = *(const bf16x8*)&hbuf[p][0][g][ln][0];
            bf16x8 s0b = *(const bf16x8*)&hbuf[p][0][g][ln + 16][0];
            bf16x8 s1a = *(const bf16x8*)&hbuf[p][0][4 + g][ln][0];
            bf16x8 s1b = *(const bf16x8*)&hbuf[p][0][4 + g][ln + 16][0];
            f32x4 a0 = {0.f, 0.f, 0.f, 0.f}, a1 = {0.f, 0.f, 0.f, 0.f};
            a0 = MFMA(aWh0[0], s0a, a0);  a1 = MFMA(aWh0[0], s0b, a1);
            a0 = MFMA(aWh0[1], s1a, a0);  a1 = MFMA(aWh0[1], s1b, a1);
            a0 = MFMA(aWi0,    bx0, a0);  a1 = MFMA(aWi0,    bx1, a1);
            f32x4 t0, t1;
#pragma unroll
            for (int r = 0; r < 4; ++r) {
                t0[r] = fast_tanh(a0[r] + bs0[r]);
                t1[r] = fast_tanh(a1[r] + bs0[r]);
            }
            if (t == SEQ - 1) {
                float* hp = hsout;  // layer 0
                *(f32x4*)(hp + (size_t)(Bb + ln) * H + i0) = t0;
                *(f32x4*)(hp + (size_t)(Bb + ln + 16) * H + i0) = t1;
            }
            bf16x4 p0v, p1v;
#pragma unroll
            for (int r = 0; r < 4; ++r) { p0v[r] = f2bf(t0[r]); p1v[r] = f2bf(t1[r]); }
            *(bf16x4*)&hbuf[q][0][kgw][ln][eb] = p0v;
            *(bf16x4*)&hbuf[q][0][kgw][ln + 16][eb] = p1v;
            __syncthreads();   // new h0 visible
        }
        // ============ L1: below = hbuf[q][0], self = hbuf[p][1] -> hbuf[q][1]
        {
            bf16x8 s0a = *(const bf16x8*)&hbuf[p][1][g][ln][0];
            bf16x8 s0b = *(const bf16x8*)&hbuf[p][1][g][ln + 16][0];
            bf16x8 s1a = *(const bf16x8*)&hbuf[p][1][4 + g][ln][0];
            bf16x8 s1b = *(const bf16x8*)&hbuf[p][1][4 + g][ln + 16][0];
            bf16x8 b0a = *(const bf16x8*)&hbuf[q][0][g][ln][0];
            bf16x8 b0b = *(const bf16x8*)&hbuf[q][0][g][ln + 16][0];
            bf16x8 b1a = *(const bf16x8*)&hbuf[q][0][4 + g][ln][0];
            bf16x8 b1b = *(const bf16x8*)&hbuf[q][0][4 + g][ln + 16][0];
            f32x4 a0 = {0.f, 0.f, 0.f, 0.f}, a1 = {0.f, 0.f, 0.f, 0.f};
            a0 = MFMA(aWh1[0], s0a, a0);  a1 = MFMA(aWh1[0], s0b, a1);
            a0 = MFMA(aWh1[1], s1a, a0);  a1 = MFMA(aWh1[1], s1b, a1);
            a0 = MFMA(aWi1[0], b0a, a0);  a1 = MFMA(aWi1[0], b0b, a1);
            a0 = MFMA(aWi1[1], b1a, a0);  a1 = MFMA(aWi1[1], b1b, a1);
            f32x4 t0, t1;
#pragma unroll
            for (int r = 0; r < 4; ++r) {
                t0[r] = fast_tanh(a0[r] + bs1[r]);
                t1[r] = fast_tanh(a1[r] + bs1[r]);
            }
            if (t == SEQ - 1) {
                float* hp = hsout + (size_t)NBATCH * H;  // layer 1
                *(f32x4*)(hp + (size_t)(Bb + ln) * H + i0) = t0;
                *(f32x4*)(hp + (size_t)(Bb + ln + 16) * H + i0) = t1;
            }
            bf16x4 p0v, p1v;
#pragma unroll
            for (int r = 0; r < 4; ++r) { p0v[r] = f2bf(t0[r]); p1v[r] = f2bf(t1[r]); }
            *(bf16x4*)&hbuf[q][1][kgw][ln][eb] = p0v;
            *(bf16x4*)&hbuf[q][1][kgw][ln + 16][eb] = p1v;
            __syncthreads();   // new h1 visible
        }
        // ============ L2: below = hbuf[q][1], self = hbuf[p][2] -> hbuf[q][2]
        {
            bf16x8 s0a = *(const bf16x8*)&hbuf[p][2][g][ln][0];
            bf16x8 s0b = *(const bf16x8*)&hbuf[p][2][g][ln + 16][0];
            bf16x8 s1a = *(const bf16x8*)&hbuf[p][2][4 + g][ln][0];
            bf16x8 s1b = *(const bf16x8*)&hbuf[p][2][4 + g][ln + 16][0];
            bf16x8 b0a = *(const bf16x8*)&hbuf[q][1][g][ln][0];
            bf16x8 b0b = *(const bf16x8*)&hbuf[q][1][g][ln + 16][0];
            bf16x8 b1a = *(const bf16x8*)&hbuf[q][1][4 + g][ln][0];
            bf16x8 b1b = *(const bf16x8*)&hbuf[q][1][4 + g][ln + 16][0];
            f32x4 a0 = {0.f, 0.f, 0.f, 0.f}, a1 = {0.f, 0.f, 0.f, 0.f};
            a0 = MFMA(aWh2[0], s0a, a0);  a1 = MFMA(aWh2[0], s0b, a1);
            a0 = MFMA(aWh2[1], s1a, a0);  a1 = MFMA(aWh2[1], s1b, a1);
            a0 = MFMA(aWi2[0], b0a, a0);  a1 = MFMA(aWi2[0], b0b, a1);
            a0 = MFMA(aWi2[1], b1a, a0);  a1 = MFMA(aWi2[1], b1b, a1);
            f32x4 t0, t1;
#pragma unroll
            for (int r = 0; r < 4; ++r) {
                t0[r] = fast_tanh(a0[r] + bs2[r]);
                t1[r] = fast_tanh(a1[r] + bs2[r]);
            }
            if (t == SEQ - 1) {
                float* hp = hsout + (size_t)2 * NBATCH * H;  // layer 2
                *(f32x4*)(hp + (size_t)(Bb + ln) * H + i0) = t0;
                *(f32x4*)(hp + (size_t)(Bb + ln + 16) * H + i0) = t1;
            }
            bf16x4 p0v, p1v;
#pragma unroll
            for (int r = 0; r < 4; ++r) { p0v[r] = f2bf(t0[r]); p1v[r] = f2bf(t1[r]); }
            *(bf16x4*)&hbuf[q][2][kgw][ln][eb] = p0v;
            *(bf16x4*)&hbuf[q][2][kgw][ln + 16][eb] = p1v;
            __syncthreads();   // new h2 visible
        }
    }

    // ===== logits head (f32 weights, bf16 h2). SEQ even -> final h2 in parity 0.
    {
        const int b  = tid & 31;
        const int c0 = tid >> 5;   // 0..7
        float hv[H];
#pragma unroll
        for (int kg = 0; kg < 8; ++kg) {
            bf16x8 v = *(const bf16x8*)&hbuf[0][2][kg][b][0];
#pragma unroll
            for (int j = 0; j < 8; ++j) hv[kg * 8 + j] = bf2f(v[j]);
        }
#pragma unroll 1
        for (int c = c0; c < CLS; c += 8) {
            const float* w = pWout + c * H;
            float a = pbout[c];
#pragma unroll
            for (int j = 0; j < H; ++j) a += w[j] * hv[j];
            out[(size_t)(Bb + b) * CLS + c] = a;
        }
    }
}

extern "C" void kernel_launch(void* const* d_in, const int* in_sizes, int n_in,
                              void* d_out, int out_size, void* d_ws, size_t ws_size,
                              hipStream_t stream) {
    const float* x    = (const float*)d_in[0];
    const float* h0in = (const float*)d_in[1];
    const float* Wi0  = (const float*)d_in[2];
    const float* Wh0  = (const float*)d_in[3];
    const float* bi0  = (const float*)d_in[4];
    const float* bh0  = (const float*)d_in[5];
    const float* Wi1  = (const float*)d_in[6];
    const float* Wh1  = (const float*)d_in[7];
    const float* bi1  = (const float*)d_in[8];
    const float* bh1  = (const float*)d_in[9];
    const float* Wi2  = (const float*)d_in[10];
    const float* Wh2  = (const float*)d_in[11];
    const float* bi2  = (const float*)d_in[12];
    const float* bh2  = (const float*)d_in[13];
    const float* Wout = (const float*)d_in[14];
    const float* bout = (const float*)d_in[15];
    float* out = (float*)d_out;

    dim3 grid(NBATCH / 32), block(256);
    rnn_mfma<<<grid, block, 0, stream>>>(x, h0in, Wi0, Wh0, bi0, bh0,
                                         Wi1, Wh1, bi1, bh1,
                                         Wi2, Wh2, bi2, bh2,
                                         Wout, bout, out);
}

// Round 5
// 101.435 us; speedup vs baseline: 30.1720x; 1.2794x over previous
//
#include <hip/hip_runtime.h>
#include <hip/hip_bf16.h>

#define SEQ 14
#define IN 24
#define H 64
#define CLS 10
#define NBATCH 65536

typedef __attribute__((ext_vector_type(4))) float f32x4;
typedef __attribute__((ext_vector_type(8))) short bf16x8;
typedef __attribute__((ext_vector_type(4))) short bf16x4;

#define MFMA(A, B, C) __builtin_amdgcn_mfma_f32_16x16x32_bf16(A, B, C, 0, 0, 0)
// Anti-rematerialization pin: makes the value opaque so the register
// allocator cannot re-load/re-pack weights inside the t-loop (R4: VGPR=40,
// weights reloaded from L2 every layer-step).
#define PIN(v) asm volatile("" : "+v"(v))

static __device__ __forceinline__ short f2bf(float f) {
    // Native cast -> compiler emits v_cvt_pk_bf16_f32 for pairs (m240).
    __hip_bfloat16 h = __float2bfloat16(f);
    union { __hip_bfloat16 h; short s; } u; u.h = h;
    return u.s;
}
static __device__ __forceinline__ float bf2f(short s) {
    union { unsigned u; float f; } a;
    a.u = ((unsigned)(unsigned short)s) << 16;
    return a.f;
}
static __device__ __forceinline__ float fast_tanh(float v) {
    // tanh(v) = 1 - 2/(exp(2v)+1); v_rcp (22-bit) not full-precision divide.
    float e = __expf(2.0f * v);
    return 1.0f - 2.0f * __builtin_amdgcn_rcpf(e + 1.0f);
}
static __device__ __forceinline__ bf16x8 pack8(f32x4 a, f32x4 b) {
    bf16x8 r;
    r[0] = f2bf(a[0]); r[1] = f2bf(a[1]); r[2] = f2bf(a[2]); r[3] = f2bf(a[3]);
    r[4] = f2bf(b[0]); r[5] = f2bf(b[1]); r[6] = f2bf(b[2]); r[7] = f2bf(b[3]);
    return r;
}
static __device__ __forceinline__ bf16x8 loadw8(const float* p) {
    f32x4 v0 = *(const f32x4*)p;
    f32x4 v1 = *(const f32x4*)(p + 4);
    return pack8(v0, v1);
}

// WG = 256 threads = 4 waves, 32 batch elems. wave = m-tile (16 i-rows).
// A = weights (VGPR, bf16, PINned), B = activations (LDS, bf16), D = preact.
// D layout (HW-verified): col(batch)=lane&15, row(i)=(lane>>4)*4+reg.
// hbuf double-buffered on t-parity: one barrier per layer-step.
__global__ __launch_bounds__(256, 4) void rnn_mfma(
    const float* __restrict__ x,     // [B, T, 24]
    const float* __restrict__ h0in,  // [3, B, 64]
    const float* __restrict__ pWi0, const float* __restrict__ pWh0,
    const float* __restrict__ pbi0, const float* __restrict__ pbh0,
    const float* __restrict__ pWi1, const float* __restrict__ pWh1,
    const float* __restrict__ pbi1, const float* __restrict__ pbh1,
    const float* __restrict__ pWi2, const float* __restrict__ pWh2,
    const float* __restrict__ pbi2, const float* __restrict__ pbh2,
    const float* __restrict__ pWout, const float* __restrict__ pbout,
    float* __restrict__ out)         // [B*10] ++ [3*B*64]
{
    __shared__ __align__(16) short hbuf[2][3][8][32][8];  // [par][layer][kg][b][e]

    const int tid  = threadIdx.x;
    const int lane = tid & 63;
    const int g    = lane >> 4;      // k-group 0..3
    const int ln   = lane & 15;      // A-row-within-tile / B-col-within-tile
    const int mt   = tid >> 6;       // wave id = m-tile 0..3
    const int Bb   = blockIdx.x * 32;

    // ---- init hbuf parity 0 from h0 (bf16) ----
    {
        const int b = tid & 31, k8 = (tid >> 5) & 7;
#pragma unroll
        for (int l = 0; l < 3; ++l) {
            const float* p = h0in + ((size_t)l * NBATCH + (Bb + b)) * H + k8 * 8;
            f32x4 v0 = *(const f32x4*)p, v1 = *(const f32x4*)(p + 4);
            *(bf16x8*)&hbuf[0][l][k8][b][0] = pack8(v0, v1);
        }
    }

    // ---- weight A-fragments (bf16, VGPR-resident, pinned) ----
    const int ia = mt * 16 + ln;     // global i-row this lane supplies for A
    bf16x8 aWi0;
    if (g < 3) aWi0 = loadw8(pWi0 + ia * IN + g * 8);
    else {
#pragma unroll
        for (int j = 0; j < 8; ++j) aWi0[j] = 0;   // k = 24..31 zero pad
    }
    PIN(aWi0);
    bf16x8 aWh0[2], aWi1[2], aWh1[2], aWi2[2], aWh2[2];
#pragma unroll
    for (int kt = 0; kt < 2; ++kt) {
        aWh0[kt] = loadw8(pWh0 + ia * H + kt * 32 + g * 8);  PIN(aWh0[kt]);
        aWi1[kt] = loadw8(pWi1 + ia * H + kt * 32 + g * 8);  PIN(aWi1[kt]);
        aWh1[kt] = loadw8(pWh1 + ia * H + kt * 32 + g * 8);  PIN(aWh1[kt]);
        aWi2[kt] = loadw8(pWi2 + ia * H + kt * 32 + g * 8);  PIN(aWi2[kt]);
        aWh2[kt] = loadw8(pWh2 + ia * H + kt * 32 + g * 8);  PIN(aWh2[kt]);
    }

    // ---- bias sums per D-row: i0 = mt*16 + g*4 + r (pinned) ----
    const int i0 = mt * 16 + g * 4;
    f32x4 bs0 = *(const f32x4*)(pbi0 + i0);
    f32x4 bs1 = *(const f32x4*)(pbi1 + i0);
    f32x4 bs2 = *(const f32x4*)(pbi2 + i0);
    bs0 += *(const f32x4*)(pbh0 + i0);
    bs1 += *(const f32x4*)(pbh1 + i0);
    bs2 += *(const f32x4*)(pbh2 + i0);
    PIN(bs0); PIN(bs1); PIN(bs2);

    const int kgw = mt * 2 + (g >> 1);   // epilogue write kg
    const int eb  = (g & 1) * 4;         // epilogue write elem base

    const float* xb0 = x + (size_t)(Bb + ln) * (SEQ * IN) + g * 8;        // nt0
    const float* xb1 = x + (size_t)(Bb + ln + 16) * (SEQ * IN) + g * 8;   // nt1
    float* hsout = out + (size_t)NBATCH * CLS;

    __syncthreads();

#pragma unroll 1
    for (int t = 0; t < SEQ; ++t) {
        const int p = t & 1, q = p ^ 1;
        // ============ L0: below = x (global), self = hbuf[p][0] -> hbuf[q][0]
        {
            bf16x8 bx0, bx1;
#pragma unroll
            for (int j = 0; j < 8; ++j) { bx0[j] = 0; bx1[j] = 0; }
            if (g < 3) {
                const float* p0 = xb0 + t * IN;
                const float* p1 = xb1 + t * IN;
                bx0 = pack8(*(const f32x4*)p0, *(const f32x4*)(p0 + 4));
                bx1 = pack8(*(const f32x4*)p1, *(const f32x4*)(p1 + 4));
            }
            bf16x8 s0a = *(const bf16x8*)&hbuf[p][0][g][ln][0];
            bf16x8 s0b = *(const bf16x8*)&hbuf[p][0][g][ln + 16][0];
            bf16x8 s1a = *(const bf16x8*)&hbuf[p][0][4 + g][ln][0];
            bf16x8 s1b = *(const bf16x8*)&hbuf[p][0][4 + g][ln + 16][0];
            f32x4 a0 = {0.f, 0.f, 0.f, 0.f}, a1 = {0.f, 0.f, 0.f, 0.f};
            a0 = MFMA(aWh0[0], s0a, a0);  a1 = MFMA(aWh0[0], s0b, a1);
            a0 = MFMA(aWh0[1], s1a, a0);  a1 = MFMA(aWh0[1], s1b, a1);
            a0 = MFMA(aWi0,    bx0, a0);  a1 = MFMA(aWi0,    bx1, a1);
            f32x4 t0, t1;
#pragma unroll
            for (int r = 0; r < 4; ++r) {
                t0[r] = fast_tanh(a0[r] + bs0[r]);
                t1[r] = fast_tanh(a1[r] + bs0[r]);
            }
            if (t == SEQ - 1) {
                float* hp = hsout;  // layer 0
                *(f32x4*)(hp + (size_t)(Bb + ln) * H + i0) = t0;
                *(f32x4*)(hp + (size_t)(Bb + ln + 16) * H + i0) = t1;
            }
            bf16x4 p0v, p1v;
#pragma unroll
            for (int r = 0; r < 4; ++r) { p0v[r] = f2bf(t0[r]); p1v[r] = f2bf(t1[r]); }
            *(bf16x4*)&hbuf[q][0][kgw][ln][eb] = p0v;
            *(bf16x4*)&hbuf[q][0][kgw][ln + 16][eb] = p1v;
            __syncthreads();   // new h0 visible
        }
        // ============ L1: below = hbuf[q][0], self = hbuf[p][1] -> hbuf[q][1]
        {
            bf16x8 s0a = *(const bf16x8*)&hbuf[p][1][g][ln][0];
            bf16x8 s0b = *(const bf16x8*)&hbuf[p][1][g][ln + 16][0];
            bf16x8 s1a = *(const bf16x8*)&hbuf[p][1][4 + g][ln][0];
            bf16x8 s1b = *(const bf16x8*)&hbuf[p][1][4 + g][ln + 16][0];
            bf16x8 b0a = *(const bf16x8*)&hbuf[q][0][g][ln][0];
            bf16x8 b0b = *(const bf16x8*)&hbuf[q][0][g][ln + 16][0];
            bf16x8 b1a = *(const bf16x8*)&hbuf[q][0][4 + g][ln][0];
            bf16x8 b1b = *(const bf16x8*)&hbuf[q][0][4 + g][ln + 16][0];
            f32x4 a0 = {0.f, 0.f, 0.f, 0.f}, a1 = {0.f, 0.f, 0.f, 0.f};
            a0 = MFMA(aWh1[0], s0a, a0);  a1 = MFMA(aWh1[0], s0b, a1);
            a0 = MFMA(aWh1[1], s1a, a0);  a1 = MFMA(aWh1[1], s1b, a1);
            a0 = MFMA(aWi1[0], b0a, a0);  a1 = MFMA(aWi1[0], b0b, a1);
            a0 = MFMA(aWi1[1], b1a, a0);  a1 = MFMA(aWi1[1], b1b, a1);
            f32x4 t0, t1;
#pragma unroll
            for (int r = 0; r < 4; ++r) {
                t0[r] = fast_tanh(a0[r] + bs1[r]);
                t1[r] = fast_tanh(a1[r] + bs1[r]);
            }
            if (t == SEQ - 1) {
                float* hp = hsout + (size_t)NBATCH * H;  // layer 1
                *(f32x4*)(hp + (size_t)(Bb + ln) * H + i0) = t0;
                *(f32x4*)(hp + (size_t)(Bb + ln + 16) * H + i0) = t1;
            }
            bf16x4 p0v, p1v;
#pragma unroll
            for (int r = 0; r < 4; ++r) { p0v[r] = f2bf(t0[r]); p1v[r] = f2bf(t1[r]); }
            *(bf16x4*)&hbuf[q][1][kgw][ln][eb] = p0v;
            *(bf16x4*)&hbuf[q][1][kgw][ln + 16][eb] = p1v;
            __syncthreads();   // new h1 visible
        }
        // ============ L2: below = hbuf[q][1], self = hbuf[p][2] -> hbuf[q][2]
        {
            bf16x8 s0a = *(const bf16x8*)&hbuf[p][2][g][ln][0];
            bf16x8 s0b = *(const bf16x8*)&hbuf[p][2][g][ln + 16][0];
            bf16x8 s1a = *(const bf16x8*)&hbuf[p][2][4 + g][ln][0];
            bf16x8 s1b = *(const bf16x8*)&hbuf[p][2][4 + g][ln + 16][0];
            bf16x8 b0a = *(const bf16x8*)&hbuf[q][1][g][ln][0];
            bf16x8 b0b = *(const bf16x8*)&hbuf[q][1][g][ln + 16][0];
            bf16x8 b1a = *(const bf16x8*)&hbuf[q][1][4 + g][ln][0];
            bf16x8 b1b = *(const bf16x8*)&hbuf[q][1][4 + g][ln + 16][0];
            f32x4 a0 = {0.f, 0.f, 0.f, 0.f}, a1 = {0.f, 0.f, 0.f, 0.f};
            a0 = MFMA(aWh2[0], s0a, a0);  a1 = MFMA(aWh2[0], s0b, a1);
            a0 = MFMA(aWh2[1], s1a, a0);  a1 = MFMA(aWh2[1], s1b, a1);
            a0 = MFMA(aWi2[0], b0a, a0);  a1 = MFMA(aWi2[0], b0b, a1);
            a0 = MFMA(aWi2[1], b1a, a0);  a1 = MFMA(aWi2[1], b1b, a1);
            f32x4 t0, t1;
#pragma unroll
            for (int r = 0; r < 4; ++r) {
                t0[r] = fast_tanh(a0[r] + bs2[r]);
                t1[r] = fast_tanh(a1[r] + bs2[r]);
            }
            if (t == SEQ - 1) {
                float* hp = hsout + (size_t)2 * NBATCH * H;  // layer 2
                *(f32x4*)(hp + (size_t)(Bb + ln) * H + i0) = t0;
                *(f32x4*)(hp + (size_t)(Bb + ln + 16) * H + i0) = t1;
            }
            bf16x4 p0v, p1v;
#pragma unroll
            for (int r = 0; r < 4; ++r) { p0v[r] = f2bf(t0[r]); p1v[r] = f2bf(t1[r]); }
            *(bf16x4*)&hbuf[q][2][kgw][ln][eb] = p0v;
            *(bf16x4*)&hbuf[q][2][kgw][ln + 16][eb] = p1v;
            __syncthreads();   // new h2 visible
        }
    }

    // ===== logits head (f32 weights, bf16 h2). SEQ even -> final h2 in parity 0.
    {
        const int b  = tid & 31;
        const int c0 = tid >> 5;   // 0..7
        float hv[H];
#pragma unroll
        for (int kg = 0; kg < 8; ++kg) {
            bf16x8 v = *(const bf16x8*)&hbuf[0][2][kg][b][0];
#pragma unroll
            for (int j = 0; j < 8; ++j) hv[kg * 8 + j] = bf2f(v[j]);
        }
#pragma unroll 1
        for (int c = c0; c < CLS; c += 8) {
            const float* w = pWout + c * H;
            float a = pbout[c];
#pragma unroll
            for (int j = 0; j < H; ++j) a += w[j] * hv[j];
            out[(size_t)(Bb + b) * CLS + c] = a;
        }
    }
}

extern "C" void kernel_launch(void* const* d_in, const int* in_sizes, int n_in,
                              void* d_out, int out_size, void* d_ws, size_t ws_size,
                              hipStream_t stream) {
    const float* x    = (const float*)d_in[0];
    const float* h0in = (const float*)d_in[1];
    const float* Wi0  = (const float*)d_in[2];
    const float* Wh0  = (const float*)d_in[3];
    const float* bi0  = (const float*)d_in[4];
    const float* bh0  = (const float*)d_in[5];
    const float* Wi1  = (const float*)d_in[6];
    const float* Wh1  = (const float*)d_in[7];
    const float* bi1  = (const float*)d_in[8];
    const float* bh1  = (const float*)d_in[9];
    const float* Wi2  = (const float*)d_in[10];
    const float* Wh2  = (const float*)d_in[11];
    const float* bi2  = (const float*)d_in[12];
    const float* bh2  = (const float*)d_in[13];
    const float* Wout = (const float*)d_in[14];
    const float* bout = (const float*)d_in[15];
    float* out = (float*)d_out;

    dim3 grid(NBATCH / 32), block(256);
    rnn_mfma<<<grid, block, 0, stream>>>(x, h0in, Wi0, Wh0, bi0, bh0,
                                         Wi1, Wh1, bi1, bh1,
                                         Wi2, Wh2, bi2, bh2,
                                         Wout, bout, out);
}